// Round 6
// baseline (411.215 us; speedup 1.0000x reference)
//
#include <hip/hip_runtime.h>
#include <cstdint>
#include <cstddef>

typedef unsigned short u16;
typedef unsigned int   u32;
typedef unsigned short u16x4 __attribute__((ext_vector_type(4)));
typedef unsigned short u16x8 __attribute__((ext_vector_type(8)));
typedef unsigned int   u32x2 __attribute__((ext_vector_type(2)));
typedef __bf16 bf16x8 __attribute__((ext_vector_type(8)));
typedef float f32x4 __attribute__((ext_vector_type(4)));

#define MFMA16(a, b, c) __builtin_amdgcn_mfma_f32_16x16x32_bf16((a), (b), (c), 0, 0, 0)

__device__ __forceinline__ float bf2f(u16 h) {
  union { unsigned u; float f; } v; v.u = ((unsigned)h) << 16; return v.f;
}
__device__ __forceinline__ u16 f2bf(float f) {
  union { float f; unsigned u; } v; v.f = f;
  unsigned r = v.u + 0x7fffu + ((v.u >> 16) & 1u);
  return (u16)(r >> 16);
}
__device__ __forceinline__ void gll16(const u16* g, u16* l) {
  __builtin_amdgcn_global_load_lds(
      (const __attribute__((address_space(1))) void*)g,
      (__attribute__((address_space(3))) void*)l, 16, 0, 0);
}
__device__ __forceinline__ float fast_exp2(float x) {
#if __has_builtin(__builtin_amdgcn_exp2f)
  return __builtin_amdgcn_exp2f(x);
#else
  return exp2f(x);
#endif
}

// ---------------------------------------------------------------------------
// Fused prologue: one dispatch replaces prep_small + cvt_x + transpose_qkv +
// transpose_w (all mutually independent). Block-id ranges:
//   [0,28)            prep_small  (biasq 3072 + madd2 4096)
//   [28,4124)         cvt_x       (f32 x -> bf16 xb, 4M elems)
//   [4124,7196)       transpose_qkv (3072 tile-blocks; Wq pre-scaled)
//   [7196,16412)      transpose_w   (Wo 1024 + W1 4096 + W2 4096 blocks)
// ---------------------------------------------------------------------------
__global__ __launch_bounds__(256) void prep_all(
    const float* __restrict__ bq, const float* __restrict__ bk,
    const float* __restrict__ bv, const int* __restrict__ mask,
    float* __restrict__ biasq, float* __restrict__ madd2,
    const float* __restrict__ x, u16* __restrict__ xb,
    const float* __restrict__ Wq, const float* __restrict__ Wk,
    const float* __restrict__ Wv, u16* __restrict__ Wqkv_t,
    const float* __restrict__ Wo, const float* __restrict__ W1,
    const float* __restrict__ W2, u16* __restrict__ Wo_t,
    u16* __restrict__ W1_t, u16* __restrict__ W2_t) {
  __shared__ u16 tile[32][33];
  const int id = blockIdx.x;
  const int tid = threadIdx.x;

  if (id < 28) {
    int i = id * 256 + tid;
    if (i < 3072) {
      biasq[i] = (i < 1024) ? bq[i] * 0.18033688f
                            : (i < 2048 ? bk[i - 1024] : bv[i - 2048]);
    } else if (i < 7168) {
      int j = i - 3072;
      madd2[j] = mask[j] ? -23.083120f : -1.442695e9f;  // (-16|-1e9)*log2e
    }
    return;
  }
  if (id < 4124) {
    int i = ((id - 28) * 256 + tid) * 4;
    const float4 v = *(const float4*)&x[i];
    u16x4 o;
    o[0] = f2bf(v.x); o[1] = f2bf(v.y); o[2] = f2bf(v.z); o[3] = f2bf(v.w);
    *(u16x4*)&xb[i] = o;
    return;
  }
  if (id < 7196) {
    // transpose_qkv: t = z*64 + y*2 + x  (x:2, y:32, z:48)
    int t = id - 4124;
    const int bx = t & 1, by = (t >> 1) & 31, z = t >> 6;
    const int which = z >> 4, h = z & 15;
    const float* in = (which == 0 ? Wq : (which == 1 ? Wk : Wv)) + (size_t)h * 1024 * 64;
    u16* out = Wqkv_t + ((size_t)which * 1024 + h * 64) * 1024;   // [64][1024]
    const float sc = (which == 0) ? 0.18033688f : 1.0f;           // 0.125*log2e
    const int tx = tid & 31, ty = tid >> 5;
    const int r0 = by * 32, c0 = bx * 32;
    #pragma unroll
    for (int i = 0; i < 32; i += 8)
      tile[ty + i][tx] = f2bf(in[(size_t)(r0 + ty + i) * 64 + c0 + tx] * sc);
    __syncthreads();
    #pragma unroll
    for (int i = 0; i < 32; i += 8)
      out[(size_t)(c0 + ty + i) * 1024 + r0 + tx] = tile[tx][ty + i];
    return;
  }
  {
    int t0 = id - 7196;
    const float* in; u16* outp; int R, C, cx, ry;
    if (t0 < 1024)      { in = Wo; outp = Wo_t; R = 1024; C = 1024; cx = t0 & 31;  ry = t0 >> 5; }
    else if (t0 < 5120) { int t = t0 - 1024; in = W1; outp = W1_t; R = 1024; C = 4096; cx = t & 127; ry = t >> 7; }
    else                { int t = t0 - 5120; in = W2; outp = W2_t; R = 4096; C = 1024; cx = t & 31;  ry = t >> 5; }
    const int tx = tid & 31, ty = tid >> 5;
    const int r0 = ry * 32, c0 = cx * 32;
    #pragma unroll
    for (int i = 0; i < 32; i += 8)
      tile[ty + i][tx] = f2bf(in[(size_t)(r0 + ty + i) * C + c0 + tx]);
    __syncthreads();
    #pragma unroll
    for (int i = 0; i < 32; i += 8)
      outp[(size_t)(c0 + ty + i) * R + r0 + tx] = tile[tx][ty + i];
  }
}

// XCD-chunked tile remap (T1). nwg must be %8==0 (all our grids are).
__device__ __forceinline__ void xcd_tiles(int& m0, int& n0) {
  const int gX = gridDim.x, gY = gridDim.y;
  int n = blockIdx.y * gX + blockIdx.x;          // hw dispatch-linear id
  int cpx = (gX * gY) >> 3;
  int t = (n & 7) * cpx + (n >> 3);              // bijective when nwg%8==0
  n0 = (t / gY) * 128;
  m0 = (t % gY) * 128;
}

// ---------------------------------------------------------------------------
// GEMM 128x128, BK=64, bf16 in/out. MODE 0: plain, 1: relu.
// ---------------------------------------------------------------------------
template <int MODE>
__global__ __launch_bounds__(256) void gemm_bt(
    const u16* __restrict__ A, const u16* __restrict__ Bt,
    const float* __restrict__ bias, u16* __restrict__ C,
    int M, int N, int K) {
  __shared__ __align__(16) u16 As[2][128 * 32];
  __shared__ __align__(16) u16 Bs[2][128 * 32];
  const int tid = threadIdx.x;
  const int lane = tid & 63;
  const int wave = tid >> 6;
  int m0, n0;
  xcd_tiles(m0, n0);
  const int wr = (wave >> 1) * 64;
  const int wc = (wave & 1) * 64;
  const int lrow = lane & 15;
  const int quad = lane >> 4;

  const int srow = lane >> 2;          // 0..15
  const int scol = (lane & 3) * 8;     // u16 col
  const u16* gA1 = &A[(size_t)(m0 + wave * 16 + srow) * K + scol];
  const u16* gA2 = &A[(size_t)(m0 + 64 + wave * 16 + srow) * K + scol];
  const u16* gB1 = &Bt[(size_t)(n0 + wave * 16 + srow) * K + scol];
  const u16* gB2 = &Bt[(size_t)(n0 + 64 + wave * 16 + srow) * K + scol];
  const int so1 = (wave * 16) * 32;
  const int so2 = (wave * 16 + 64) * 32;

  f32x4 acc[4][4];
  #pragma unroll
  for (int i = 0; i < 4; ++i)
    #pragma unroll
    for (int j = 0; j < 4; ++j)
      acc[i][j] = (f32x4){0.f, 0.f, 0.f, 0.f};

  for (int k0 = 0; k0 < K; k0 += 64) {
    gll16(gA1 + k0, &As[0][so1]);
    gll16(gA2 + k0, &As[0][so2]);
    gll16(gB1 + k0, &Bs[0][so1]);
    gll16(gB2 + k0, &Bs[0][so2]);
    gll16(gA1 + k0 + 32, &As[1][so1]);
    gll16(gA2 + k0 + 32, &As[1][so2]);
    gll16(gB1 + k0 + 32, &Bs[1][so1]);
    gll16(gB2 + k0 + 32, &Bs[1][so2]);
    __syncthreads();
    #pragma unroll
    for (int kb = 0; kb < 2; ++kb) {
      bf16x8 af[4], bfr[4];
      #pragma unroll
      for (int i = 0; i < 4; ++i) {
        af[i]  = *(const bf16x8*)&As[kb][(wr + i * 16 + lrow) * 32 + quad * 8];
        bfr[i] = *(const bf16x8*)&Bs[kb][(wc + i * 16 + lrow) * 32 + quad * 8];
      }
      #pragma unroll
      for (int fr = 0; fr < 4; ++fr)
        #pragma unroll
        for (int fc = 0; fc < 4; ++fc)
          acc[fr][fc] = MFMA16(af[fr], bfr[fc], acc[fr][fc]);
    }
    __syncthreads();
  }

  #pragma unroll
  for (int fr = 0; fr < 4; ++fr) {
    int rowb = m0 + wr + fr * 16 + quad * 4;
    #pragma unroll
    for (int fc = 0; fc < 4; ++fc) {
      int col = n0 + wc + fc * 16 + lrow;
      float bv = bias[col];
      #pragma unroll
      for (int r = 0; r < 4; ++r) {
        float v = acc[fr][fc][r] + bv;
        if (MODE == 1) v = fmaxf(v, 0.f);
        C[(size_t)(rowb + r) * N + col] = f2bf(v);
      }
    }
  }
}

// ---------------------------------------------------------------------------
// Split-K GEMM 128x128, BK=64: grid (N/128, M/128, 2).
// ---------------------------------------------------------------------------
__global__ __launch_bounds__(256) void gemm_splitk(
    const u16* __restrict__ A, const u16* __restrict__ Bt,
    u16* __restrict__ Cp, int M, int N, int K) {
  __shared__ __align__(16) u16 As[2][128 * 32];
  __shared__ __align__(16) u16 Bs[2][128 * 32];
  const int tid = threadIdx.x;
  const int lane = tid & 63;
  const int wave = tid >> 6;
  int m0, n0;
  xcd_tiles(m0, n0);
  const int kz = blockIdx.z;
  const int Kh = K >> 1;
  const int kbase = kz * Kh;
  const int wr = (wave >> 1) * 64;
  const int wc = (wave & 1) * 64;
  const int lrow = lane & 15;
  const int quad = lane >> 4;

  const int srow = lane >> 2;
  const int scol = (lane & 3) * 8;
  const u16* gA1 = &A[(size_t)(m0 + wave * 16 + srow) * K + kbase + scol];
  const u16* gA2 = &A[(size_t)(m0 + 64 + wave * 16 + srow) * K + kbase + scol];
  const u16* gB1 = &Bt[(size_t)(n0 + wave * 16 + srow) * K + kbase + scol];
  const u16* gB2 = &Bt[(size_t)(n0 + 64 + wave * 16 + srow) * K + kbase + scol];
  const int so1 = (wave * 16) * 32;
  const int so2 = (wave * 16 + 64) * 32;
  u16* C = Cp + (size_t)kz * M * N;

  f32x4 acc[4][4];
  #pragma unroll
  for (int i = 0; i < 4; ++i)
    #pragma unroll
    for (int j = 0; j < 4; ++j)
      acc[i][j] = (f32x4){0.f, 0.f, 0.f, 0.f};

  for (int k0 = 0; k0 < Kh; k0 += 64) {
    gll16(gA1 + k0, &As[0][so1]);
    gll16(gA2 + k0, &As[0][so2]);
    gll16(gB1 + k0, &Bs[0][so1]);
    gll16(gB2 + k0, &Bs[0][so2]);
    gll16(gA1 + k0 + 32, &As[1][so1]);
    gll16(gA2 + k0 + 32, &As[1][so2]);
    gll16(gB1 + k0 + 32, &Bs[1][so1]);
    gll16(gB2 + k0 + 32, &Bs[1][so2]);
    __syncthreads();
    #pragma unroll
    for (int kb = 0; kb < 2; ++kb) {
      bf16x8 af[4], bfr[4];
      #pragma unroll
      for (int i = 0; i < 4; ++i) {
        af[i]  = *(const bf16x8*)&As[kb][(wr + i * 16 + lrow) * 32 + quad * 8];
        bfr[i] = *(const bf16x8*)&Bs[kb][(wc + i * 16 + lrow) * 32 + quad * 8];
      }
      #pragma unroll
      for (int fr = 0; fr < 4; ++fr)
        #pragma unroll
        for (int fc = 0; fc < 4; ++fc)
          acc[fr][fc] = MFMA16(af[fr], bfr[fc], acc[fr][fc]);
    }
    __syncthreads();
  }

  #pragma unroll
  for (int fr = 0; fr < 4; ++fr) {
    int rowb = m0 + wr + fr * 16 + quad * 4;
    #pragma unroll
    for (int fc = 0; fc < 4; ++fc) {
      int col = n0 + wc + fc * 16 + lrow;
      #pragma unroll
      for (int r = 0; r < 4; ++r)
        C[(size_t)(rowb + r) * N + col] = f2bf(acc[fr][fc][r]);
    }
  }
}

// ---------------------------------------------------------------------------
// Flash attention — r5 structure with KVBLK 64->128: same grid (16,16,2),
// same 2-barrier-per-staging pattern, t=2 q-tiles/wave, but staging/barrier
// instances HALVED (16 steps of 128 keys). Softmax+PV run in two 64-key
// passes per step so Ps stays [16][72] and the fragment live-set stays 64
// VGPRs (kf/vf loaded per half). LDS = 18432(Ks[128][72]) + 17408(Vt[64][136])
// + 18432(Ps) = 54272 B. p = exp2(z + madd) (Wq pre-scaled by 0.125*log2e).
// ---------------------------------------------------------------------------
__global__ __launch_bounds__(256) void attn_kernel(
    const u16* __restrict__ xqkv, const float* __restrict__ madd2,
    u16* __restrict__ ctx) {
  __shared__ __align__(16) u16 Ks[128][72];
  __shared__ __align__(16) u16 Vt[64][136];
  __shared__ __align__(16) u16 Ps[4][2][16][72];
  const int tid = threadIdx.x;
  const int lane = tid & 63;
  const int wave = tid >> 6;
  const int lrow = lane & 15;
  const int quad = lane >> 4;
  const int b = blockIdx.z, h = blockIdx.y;
  const int qb = blockIdx.x * 128 + wave * 16;
  const u16* Qp = xqkv + (size_t)b * 2048 * 3072 + h * 64;
  const u16* Kp = Qp + 1024;
  const u16* Vp = Qp + 2048;

  bf16x8 qa[2][2];
  #pragma unroll
  for (int t = 0; t < 2; ++t) {
    qa[t][0] = *(const bf16x8*)&Qp[(size_t)(qb + t * 64 + lrow) * 3072 + quad * 8];
    qa[t][1] = *(const bf16x8*)&Qp[(size_t)(qb + t * 64 + lrow) * 3072 + 32 + quad * 8];
  }

  f32x4 o[2][4];
  #pragma unroll
  for (int t = 0; t < 2; ++t)
    #pragma unroll
    for (int i = 0; i < 4; ++i) o[t][i] = (f32x4){0.f, 0.f, 0.f, 0.f};
  float rsum[2] = {0.f, 0.f};

  const int ks_row = tid >> 3, ks_col = (tid & 7) * 8;  // rows 0..31, cols 0..56
  const int v_dg = tid >> 4;                             // 0..15
  const int v_kp = tid & 15;
  const float* maddb = madd2 + b * 2048;

  u16x8 kreg[4];
  u16x4 va[4], vb[4];
  #pragma unroll
  for (int sh = 0; sh < 4; ++sh) {
    kreg[sh] = *(const u16x8*)&Kp[(size_t)(sh * 32 + ks_row) * 3072 + ks_col];
    va[sh] = *(const u16x4*)&Vp[(size_t)(sh * 32 + 2 * v_kp) * 3072 + v_dg * 4];
    vb[sh] = *(const u16x4*)&Vp[(size_t)(sh * 32 + 2 * v_kp + 1) * 3072 + v_dg * 4];
  }

  for (int s0 = 0; s0 < 2048; s0 += 128) {
    __syncthreads();
    #pragma unroll
    for (int sh = 0; sh < 4; ++sh) {
      *(u16x8*)&Ks[sh * 32 + ks_row][ks_col] = kreg[sh];
      #pragma unroll
      for (int j = 0; j < 4; ++j) {
        u32 pk = ((u32)vb[sh][j] << 16) | (u32)va[sh][j];
        *(u32*)&Vt[v_dg * 4 + j][sh * 32 + 2 * v_kp] = pk;
      }
    }
    __syncthreads();
    if (s0 + 128 < 2048) {
      #pragma unroll
      for (int sh = 0; sh < 4; ++sh) {
        int sb = s0 + 128 + sh * 32;
        kreg[sh] = *(const u16x8*)&Kp[(size_t)(sb + ks_row) * 3072 + ks_col];
        va[sh] = *(const u16x4*)&Vp[(size_t)(sb + 2 * v_kp) * 3072 + v_dg * 4];
        vb[sh] = *(const u16x4*)&Vp[(size_t)(sb + 2 * v_kp + 1) * 3072 + v_dg * 4];
      }
    }

    #pragma unroll
    for (int h2 = 0; h2 < 2; ++h2) {
      bf16x8 kf[4][2], vf[4][2];
      #pragma unroll
      for (int kb = 0; kb < 4; ++kb) {
        kf[kb][0] = *(const bf16x8*)&Ks[h2 * 64 + kb * 16 + lrow][quad * 8];
        kf[kb][1] = *(const bf16x8*)&Ks[h2 * 64 + kb * 16 + lrow][32 + quad * 8];
      }
      #pragma unroll
      for (int nb = 0; nb < 4; ++nb) {
        vf[nb][0] = *(const bf16x8*)&Vt[nb * 16 + lrow][(h2 * 2 + 0) * 32 + quad * 8];
        vf[nb][1] = *(const bf16x8*)&Vt[nb * 16 + lrow][(h2 * 2 + 1) * 32 + quad * 8];
      }

      #pragma unroll
      for (int t = 0; t < 2; ++t) {
        #pragma unroll
        for (int kb = 0; kb < 4; ++kb) {
          f32x4 z = (f32x4){0.f, 0.f, 0.f, 0.f};
          z = MFMA16(kf[kb][0], qa[t][0], z);
          z = MFMA16(kf[kb][1], qa[t][1], z);
          f32x4 m4 = *(const f32x4*)&maddb[s0 + h2 * 64 + kb * 16 + quad * 4];
          u32 pb[4];
          #pragma unroll
          for (int r = 0; r < 4; ++r) {
            float p = fast_exp2(z[r] + m4[r]);
            rsum[t] += p;
            union { float f; u32 u; } cv; cv.f = p;
            pb[r] = cv.u + 0x8000u;
          }
          u32x2 w2;
          w2[0] = __builtin_amdgcn_perm(pb[1], pb[0], 0x07060302);
          w2[1] = __builtin_amdgcn_perm(pb[3], pb[2], 0x07060302);
          *(u32x2*)&Ps[wave][t][lrow][kb * 16 + quad * 4] = w2;
        }
        #pragma unroll
        for (int kh = 0; kh < 2; ++kh) {
          bf16x8 pa = *(const bf16x8*)&Ps[wave][t][lrow][kh * 32 + quad * 8];
          #pragma unroll
          for (int nb = 0; nb < 4; ++nb)
            o[t][nb] = MFMA16(pa, vf[nb][kh], o[t][nb]);
        }
      }
    }
  }

  #pragma unroll
  for (int t = 0; t < 2; ++t) {
    float rs = rsum[t];
    rs += __shfl_xor(rs, 16, 64);
    rs += __shfl_xor(rs, 32, 64);
    float inv = 1.f / fmaxf(rs, 1e-30f);
    #pragma unroll
    for (int r = 0; r < 4; ++r) {
      float invq = __shfl(inv, quad * 4 + r, 64);
      int q = qb + t * 64 + quad * 4 + r;
      #pragma unroll
      for (int nb = 0; nb < 4; ++nb) {
        float v = o[t][nb][r] * invq;
        ctx[((size_t)b * 2048 + q) * 1024 + h * 64 + nb * 16 + lrow] = f2bf(v);
      }
    }
  }
}

// ---------------------------------------------------------------------------
// out = LayerNorm(x + p0 + p1 + cb) * g + b  (split-K combine fused in).
// ---------------------------------------------------------------------------
template <int IN_BF, int OUT_BF>
__global__ __launch_bounds__(256) void add_ln2p(
    const void* __restrict__ xa_, const u16* __restrict__ p0,
    const u16* __restrict__ p1, const float* __restrict__ cb,
    const float* __restrict__ g, const float* __restrict__ bb,
    void* __restrict__ outp_) {
  __shared__ float red[8];
  const int tid = threadIdx.x;
  const size_t base = (size_t)blockIdx.x * 1024;
  const float* xf = (const float*)xa_;
  const u16*   xb = (const u16*)xa_;
  float v[4];
  float s = 0.f;
  #pragma unroll
  for (int i = 0; i < 4; ++i) {
    int c = i * 256 + tid;
    float xv = IN_BF ? bf2f(xb[base + c]) : xf[base + c];
    v[i] = xv + bf2f(p0[base + c]) + bf2f(p1[base + c]) + cb[c];
    s += v[i];
  }
  #pragma unroll
  for (int off = 32; off > 0; off >>= 1) s += __shfl_down(s, off, 64);
  if ((tid & 63) == 0) red[tid >> 6] = s;
  __syncthreads();
  float mean = (red[0] + red[1] + red[2] + red[3]) * (1.f / 1024.f);
  float s2 = 0.f;
  #pragma unroll
  for (int i = 0; i < 4; ++i) { float d = v[i] - mean; s2 += d * d; }
  #pragma unroll
  for (int off = 32; off > 0; off >>= 1) s2 += __shfl_down(s2, off, 64);
  if ((tid & 63) == 0) red[4 + (tid >> 6)] = s2;
  __syncthreads();
  float var = (red[4] + red[5] + red[6] + red[7]) * (1.f / 1024.f);
  float rstd = rsqrtf(var + 1e-5f);
  #pragma unroll
  for (int i = 0; i < 4; ++i) {
    int c = i * 256 + tid;
    float r = (v[i] - mean) * rstd * g[c] + bb[c];
    if (OUT_BF) ((u16*)outp_)[base + c] = f2bf(r);
    else        ((float*)outp_)[base + c] = r;
  }
}

// ---------------------------------------------------------------------------
extern "C" void kernel_launch(void* const* d_in, const int* in_sizes, int n_in,
                              void* d_out, int out_size, void* d_ws, size_t ws_size,
                              hipStream_t stream) {
  (void)in_sizes; (void)n_in; (void)out_size; (void)ws_size;
  const float* x    = (const float*)d_in[0];
  const int*   mask = (const int*)d_in[1];
  const float* Wq   = (const float*)d_in[2];
  const float* bq   = (const float*)d_in[3];
  const float* Wk   = (const float*)d_in[4];
  const float* bk   = (const float*)d_in[5];
  const float* Wv   = (const float*)d_in[6];
  const float* bv   = (const float*)d_in[7];
  const float* Wo   = (const float*)d_in[8];
  const float* bo   = (const float*)d_in[9];
  const float* ln1g = (const float*)d_in[10];
  const float* ln1b = (const float*)d_in[11];
  const float* ln2g = (const float*)d_in[12];
  const float* ln2b = (const float*)d_in[13];
  const float* W1   = (const float*)d_in[14];
  const float* b1   = (const float*)d_in[15];
  const float* W2   = (const float*)d_in[16];
  const float* b2   = (const float*)d_in[17];
  float* out = (float*)d_out;

  char* ws = (char*)d_ws;
  u16*   Wqkv_t = (u16*)(ws + 0);           // 6 MB; later FF2 partial0 (8 MB)
  u16*   fp     = (u16*)(ws + 0);           // FF2 partials: [0,8M) + [8M,16M)
  u16*   Wo_t   = (u16*)(ws + 6291456);     // 2 MB
  u16*   W1_t   = (u16*)(ws + 8388608);     // 8 MB; later FF2 partial1
  u16*   W2_t   = (u16*)(ws + 16777216);    // 8 MB
  u16*   xqkv   = (u16*)(ws + 25165824);    // [4096][3072] bf16, 24 MB
  u16*   wp     = (u16*)(ws + 25165824);    // Wo partials 2x8 MB (xqkv dead after attn)
  u16*   xb     = (u16*)(ws + 50331648);    // 8 MB (dead after QKV gemm)
  u16*   ctx    = (u16*)(ws + 50331648);    // [4096][1024] bf16, 8 MB (after attn)
  u16*   ff1    = (u16*)(ws + 25165824);    // 32 MB (overlays xqkv+ctx; live LN1->FF2)
  u16*   hbuf   = (u16*)(ws + 67108864);    // 8 MB
  float* biasq  = (float*)(ws + 75497472);  // 3072 f32
  float* madd2  = (float*)(ws + 75509760);  // 4096 f32  (total ~75.5 MB)

  prep_all<<<16412, 256, 0, stream>>>(bq, bk, bv, mask, biasq, madd2,
                                      x, xb, Wq, Wk, Wv, Wqkv_t,
                                      Wo, W1, W2, Wo_t, W1_t, W2_t);

  gemm_bt<0><<<dim3(24, 32), 256, 0, stream>>>(xb, Wqkv_t, biasq, xqkv,
                                               4096, 3072, 1024);
  attn_kernel<<<dim3(16, 16, 2), 256, 0, stream>>>(xqkv, madd2, ctx);
  // Wo projection, split-K=2 -> bf16 partials in dead xqkv space
  gemm_splitk<<<dim3(8, 32, 2), 256, 0, stream>>>(ctx, Wo_t, wp, 4096, 1024, 1024);
  add_ln2p<0, 1><<<4096, 256, 0, stream>>>(x, wp, wp + 4194304, bo,
                                           ln1g, ln1b, hbuf);
  gemm_bt<1><<<dim3(32, 32), 256, 0, stream>>>(hbuf, W1_t, b1, ff1,
                                               4096, 4096, 1024);
  // FF2, split-K=2 -> partials in dead Wqkv_t/W1_t space
  gemm_splitk<<<dim3(8, 32, 2), 256, 0, stream>>>(ff1, W2_t, fp, 4096, 1024, 4096);
  add_ln2p<1, 0><<<4096, 256, 0, stream>>>(hbuf, fp, fp + 4194304, b2,
                                           ln2g, ln2b, out);
}

// Round 7
// 366.443 us; speedup vs baseline: 1.1222x; 1.1222x over previous
//
#include <hip/hip_runtime.h>
#include <cstdint>
#include <cstddef>

typedef unsigned short u16;
typedef unsigned int   u32;
typedef unsigned short u16x4 __attribute__((ext_vector_type(4)));
typedef unsigned short u16x8 __attribute__((ext_vector_type(8)));
typedef unsigned int   u32x2 __attribute__((ext_vector_type(2)));
typedef __bf16 bf16x8 __attribute__((ext_vector_type(8)));
typedef float f32x4 __attribute__((ext_vector_type(4)));

#define MFMA16(a, b, c) __builtin_amdgcn_mfma_f32_16x16x32_bf16((a), (b), (c), 0, 0, 0)

__device__ __forceinline__ float bf2f(u16 h) {
  union { unsigned u; float f; } v; v.u = ((unsigned)h) << 16; return v.f;
}
__device__ __forceinline__ u16 f2bf(float f) {
  union { float f; unsigned u; } v; v.f = f;
  unsigned r = v.u + 0x7fffu + ((v.u >> 16) & 1u);
  return (u16)(r >> 16);
}
__device__ __forceinline__ void gll16(const u16* g, u16* l) {
  __builtin_amdgcn_global_load_lds(
      (const __attribute__((address_space(1))) void*)g,
      (__attribute__((address_space(3))) void*)l, 16, 0, 0);
}
__device__ __forceinline__ float fast_exp2(float x) {
#if __has_builtin(__builtin_amdgcn_exp2f)
  return __builtin_amdgcn_exp2f(x);
#else
  return exp2f(x);
#endif
}

// ---------------------------------------------------------------------------
// Fused prologue: one dispatch replaces prep_small + cvt_x + transpose_qkv +
// transpose_w. Block-id ranges:
//   [0,28)        prep_small   [28,4124)  cvt_x
//   [4124,7196)   transpose_qkv (Wq pre-scaled by 0.125*log2e)
//   [7196,16412)  transpose_w
// ---------------------------------------------------------------------------
__global__ __launch_bounds__(256) void prep_all(
    const float* __restrict__ bq, const float* __restrict__ bk,
    const float* __restrict__ bv, const int* __restrict__ mask,
    float* __restrict__ biasq, float* __restrict__ madd2,
    const float* __restrict__ x, u16* __restrict__ xb,
    const float* __restrict__ Wq, const float* __restrict__ Wk,
    const float* __restrict__ Wv, u16* __restrict__ Wqkv_t,
    const float* __restrict__ Wo, const float* __restrict__ W1,
    const float* __restrict__ W2, u16* __restrict__ Wo_t,
    u16* __restrict__ W1_t, u16* __restrict__ W2_t) {
  __shared__ u16 tile[32][33];
  const int id = blockIdx.x;
  const int tid = threadIdx.x;

  if (id < 28) {
    int i = id * 256 + tid;
    if (i < 3072) {
      biasq[i] = (i < 1024) ? bq[i] * 0.18033688f
                            : (i < 2048 ? bk[i - 1024] : bv[i - 2048]);
    } else if (i < 7168) {
      int j = i - 3072;
      madd2[j] = mask[j] ? -23.083120f : -1.442695e9f;  // (-16|-1e9)*log2e
    }
    return;
  }
  if (id < 4124) {
    int i = ((id - 28) * 256 + tid) * 4;
    const float4 v = *(const float4*)&x[i];
    u16x4 o;
    o[0] = f2bf(v.x); o[1] = f2bf(v.y); o[2] = f2bf(v.z); o[3] = f2bf(v.w);
    *(u16x4*)&xb[i] = o;
    return;
  }
  if (id < 7196) {
    int t = id - 4124;
    const int bx = t & 1, by = (t >> 1) & 31, z = t >> 6;
    const int which = z >> 4, h = z & 15;
    const float* in = (which == 0 ? Wq : (which == 1 ? Wk : Wv)) + (size_t)h * 1024 * 64;
    u16* out = Wqkv_t + ((size_t)which * 1024 + h * 64) * 1024;   // [64][1024]
    const float sc = (which == 0) ? 0.18033688f : 1.0f;           // 0.125*log2e
    const int tx = tid & 31, ty = tid >> 5;
    const int r0 = by * 32, c0 = bx * 32;
    #pragma unroll
    for (int i = 0; i < 32; i += 8)
      tile[ty + i][tx] = f2bf(in[(size_t)(r0 + ty + i) * 64 + c0 + tx] * sc);
    __syncthreads();
    #pragma unroll
    for (int i = 0; i < 32; i += 8)
      out[(size_t)(c0 + ty + i) * 1024 + r0 + tx] = tile[tx][ty + i];
    return;
  }
  {
    int t0 = id - 7196;
    const float* in; u16* outp; int R, C, cx, ry;
    if (t0 < 1024)      { in = Wo; outp = Wo_t; R = 1024; C = 1024; cx = t0 & 31;  ry = t0 >> 5; }
    else if (t0 < 5120) { int t = t0 - 1024; in = W1; outp = W1_t; R = 1024; C = 4096; cx = t & 127; ry = t >> 7; }
    else                { int t = t0 - 5120; in = W2; outp = W2_t; R = 4096; C = 1024; cx = t & 31;  ry = t >> 5; }
    const int tx = tid & 31, ty = tid >> 5;
    const int r0 = ry * 32, c0 = cx * 32;
    #pragma unroll
    for (int i = 0; i < 32; i += 8)
      tile[ty + i][tx] = f2bf(in[(size_t)(r0 + ty + i) * C + c0 + tx]);
    __syncthreads();
    #pragma unroll
    for (int i = 0; i < 32; i += 8)
      outp[(size_t)(c0 + ty + i) * R + r0 + tx] = tile[tx][ty + i];
  }
}

// XCD-chunked tile remap (T1), 128-tiles. nwg must be %8==0.
__device__ __forceinline__ void xcd_tiles(int& m0, int& n0) {
  const int gX = gridDim.x, gY = gridDim.y;
  int n = blockIdx.y * gX + blockIdx.x;
  int cpx = (gX * gY) >> 3;
  int t = (n & 7) * cpx + (n >> 3);
  n0 = (t / gY) * 128;
  m0 = (t % gY) * 128;
}
// 256-tile variant for gemm256.
__device__ __forceinline__ void xcd_tiles256(int& m0, int& n0) {
  const int gX = gridDim.x, gY = gridDim.y;
  int n = blockIdx.y * gX + blockIdx.x;
  int cpx = (gX * gY) >> 3;
  int t = (n & 7) * cpx + (n >> 3);
  n0 = (t / gY) * 256;
  m0 = (t % gY) * 256;
}

// ---------------------------------------------------------------------------
// gemm256: 256x256 tile, BK=64, 8 waves (512 thr), phase-split double-buffer
// (drain0 form of the 8-phase template). A [M][K], Bt [N][K], C [M][N] bf16.
// Per K-step: 4 quadrant-phases, each { ds_read A-subtile (+B at q0) |
// issue 1 half-tile (2x gll16) of step t+1 into buf p^1 | s_barrier |
// 16 MFMA | s_barrier }, then __syncthreads() (drains vmcnt+lgkm).
// Staging only targets the NON-read buffer; drain precedes its first read.
// LDS: As[2][256][64] + Bs[2][256][64] = 131072 B (dynamic).
// MODE 0: bias, 1: bias+relu.
// ---------------------------------------------------------------------------
template <int MODE>
__global__ __launch_bounds__(512, 2) void gemm256(
    const u16* __restrict__ A, const u16* __restrict__ Bt,
    const float* __restrict__ bias, u16* __restrict__ C,
    int M, int N, int K) {
  extern __shared__ __align__(16) u16 lds[];
  u16* As = lds;                 // [2][256*64]
  u16* Bs = lds + 2 * 256 * 64;
  const int tid = threadIdx.x;   // 0..511
  const int lane = tid & 63, wave = tid >> 6;
  int m0, n0;
  xcd_tiles256(m0, n0);
  const int wr = (wave >> 2) * 128;   // 0 / 128
  const int wc = (wave & 3) * 64;     // 0..192
  const int lrow = lane & 15, quad = lane >> 4;

  // staging: lane covers row wave*8 + (lane>>3), col (lane&7)*8 per sweep.
  const int g_r = wave * 8 + (lane >> 3);
  const int g_c = (lane & 7) * 8;
  const u16* gA = A + (size_t)(m0 + g_r) * K + g_c;
  const u16* gB = Bt + (size_t)(n0 + g_r) * K + g_c;
  const int wbase = wave * 512;  // wave-uniform LDS chunk (64 lanes x 8 u16)

  f32x4 acc[8][4];
  #pragma unroll
  for (int i = 0; i < 8; ++i)
    #pragma unroll
    for (int j = 0; j < 4; ++j)
      acc[i][j] = (f32x4){0.f, 0.f, 0.f, 0.f};

  const int NT = K >> 6;   // K-steps of 64

  // prologue: stage step 0 into buf 0 (4 half-tiles = 8 gll16)
  #pragma unroll
  for (int h = 0; h < 2; ++h) {
    gll16(gA + (size_t)(h * 128) * K,      As + h * 8192 + wbase);
    gll16(gA + (size_t)(h * 128 + 64) * K, As + h * 8192 + 4096 + wbase);
    gll16(gB + (size_t)(h * 128) * K,      Bs + h * 8192 + wbase);
    gll16(gB + (size_t)(h * 128 + 64) * K, Bs + h * 8192 + 4096 + wbase);
  }
  __syncthreads();

  for (int t = 0; t < NT; ++t) {
    const int p = t & 1;
    const u16* Ab = As + p * 16384;
    const u16* Bb = Bs + p * 16384;
    bf16x8 bfr[4][2];
    #pragma unroll
    for (int q = 0; q < 4; ++q) {
      if (q == 0) {
        #pragma unroll
        for (int fc = 0; fc < 4; ++fc)
          #pragma unroll
          for (int kh = 0; kh < 2; ++kh)
            bfr[fc][kh] = *(const bf16x8*)&Bb[(wc + fc * 16 + lrow) * 64 + kh * 32 + quad * 8];
      }
      bf16x8 af2[2][2];
      #pragma unroll
      for (int j = 0; j < 2; ++j)
        #pragma unroll
        for (int kh = 0; kh < 2; ++kh)
          af2[j][kh] = *(const bf16x8*)&Ab[(wr + (q * 2 + j) * 16 + lrow) * 64 + kh * 32 + quad * 8];
      if (t + 1 < NT) {
        // stage half-tile q of step t+1 into the other buffer
        const int kc = (t + 1) * 64;
        u16* dst = ((q < 2) ? As : Bs) + (p ^ 1) * 16384 + (q & 1) * 8192 + wbase;
        const u16* src = ((q < 2) ? gA : gB) + (size_t)((q & 1) * 128) * K + kc;
        gll16(src, dst);
        gll16(src + (size_t)64 * K, dst + 4096);
      }
      __builtin_amdgcn_s_barrier();
      #pragma unroll
      for (int j = 0; j < 2; ++j)
        #pragma unroll
        for (int fc = 0; fc < 4; ++fc) {
          acc[q * 2 + j][fc] = MFMA16(af2[j][0], bfr[fc][0], acc[q * 2 + j][fc]);
          acc[q * 2 + j][fc] = MFMA16(af2[j][1], bfr[fc][1], acc[q * 2 + j][fc]);
        }
      if (q < 3) __builtin_amdgcn_s_barrier();
    }
    __syncthreads();   // drains vmcnt(0)+lgkmcnt(0): buf p^1 ready, p free
  }

  #pragma unroll
  for (int fr = 0; fr < 8; ++fr) {
    int rowb = m0 + wr + fr * 16 + quad * 4;
    #pragma unroll
    for (int fc = 0; fc < 4; ++fc) {
      int col = n0 + wc + fc * 16 + lrow;
      float bv = bias[col];
      #pragma unroll
      for (int r = 0; r < 4; ++r) {
        float v = acc[fr][fc][r] + bv;
        if (MODE == 1) v = fmaxf(v, 0.f);
        C[(size_t)(rowb + r) * N + col] = f2bf(v);
      }
    }
  }
}

// ---------------------------------------------------------------------------
// Split-K GEMM 128x128, BK=64: grid (N/128, M/128, 2).
// ---------------------------------------------------------------------------
__global__ __launch_bounds__(256) void gemm_splitk(
    const u16* __restrict__ A, const u16* __restrict__ Bt,
    u16* __restrict__ Cp, int M, int N, int K) {
  __shared__ __align__(16) u16 As[2][128 * 32];
  __shared__ __align__(16) u16 Bs[2][128 * 32];
  const int tid = threadIdx.x;
  const int lane = tid & 63;
  const int wave = tid >> 6;
  int m0, n0;
  xcd_tiles(m0, n0);
  const int kz = blockIdx.z;
  const int Kh = K >> 1;
  const int kbase = kz * Kh;
  const int wr = (wave >> 1) * 64;
  const int wc = (wave & 1) * 64;
  const int lrow = lane & 15;
  const int quad = lane >> 4;

  const int srow = lane >> 2;
  const int scol = (lane & 3) * 8;
  const u16* gA1 = &A[(size_t)(m0 + wave * 16 + srow) * K + kbase + scol];
  const u16* gA2 = &A[(size_t)(m0 + 64 + wave * 16 + srow) * K + kbase + scol];
  const u16* gB1 = &Bt[(size_t)(n0 + wave * 16 + srow) * K + kbase + scol];
  const u16* gB2 = &Bt[(size_t)(n0 + 64 + wave * 16 + srow) * K + kbase + scol];
  const int so1 = (wave * 16) * 32;
  const int so2 = (wave * 16 + 64) * 32;
  u16* C = Cp + (size_t)kz * M * N;

  f32x4 acc[4][4];
  #pragma unroll
  for (int i = 0; i < 4; ++i)
    #pragma unroll
    for (int j = 0; j < 4; ++j)
      acc[i][j] = (f32x4){0.f, 0.f, 0.f, 0.f};

  for (int k0 = 0; k0 < Kh; k0 += 64) {
    gll16(gA1 + k0, &As[0][so1]);
    gll16(gA2 + k0, &As[0][so2]);
    gll16(gB1 + k0, &Bs[0][so1]);
    gll16(gB2 + k0, &Bs[0][so2]);
    gll16(gA1 + k0 + 32, &As[1][so1]);
    gll16(gA2 + k0 + 32, &As[1][so2]);
    gll16(gB1 + k0 + 32, &Bs[1][so1]);
    gll16(gB2 + k0 + 32, &Bs[1][so2]);
    __syncthreads();
    #pragma unroll
    for (int kb = 0; kb < 2; ++kb) {
      bf16x8 af[4], bfr[4];
      #pragma unroll
      for (int i = 0; i < 4; ++i) {
        af[i]  = *(const bf16x8*)&As[kb][(wr + i * 16 + lrow) * 32 + quad * 8];
        bfr[i] = *(const bf16x8*)&Bs[kb][(wc + i * 16 + lrow) * 32 + quad * 8];
      }
      #pragma unroll
      for (int fr = 0; fr < 4; ++fr)
        #pragma unroll
        for (int fc = 0; fc < 4; ++fc)
          acc[fr][fc] = MFMA16(af[fr], bfr[fc], acc[fr][fc]);
    }
    __syncthreads();
  }

  #pragma unroll
  for (int fr = 0; fr < 4; ++fr) {
    int rowb = m0 + wr + fr * 16 + quad * 4;
    #pragma unroll
    for (int fc = 0; fc < 4; ++fc) {
      int col = n0 + wc + fc * 16 + lrow;
      #pragma unroll
      for (int r = 0; r < 4; ++r)
        C[(size_t)(rowb + r) * N + col] = f2bf(acc[fr][fc][r]);
    }
  }
}

// ---------------------------------------------------------------------------
// Flash attention — r5 form verbatim (76.5 us measured): 2 barriers/step,
// t=2 q-tiles/wave, 128 q-rows/block, grid (16,16,2), no setprio.
// Vt trimmed to [64][72]; p = exp2(z + madd) (Wq pre-scaled). LDS 36864 B.
// ---------------------------------------------------------------------------
__global__ __launch_bounds__(256) void attn_kernel(
    const u16* __restrict__ xqkv, const float* __restrict__ madd2,
    u16* __restrict__ ctx) {
  __shared__ __align__(16) u16 Ks[64][72];
  __shared__ __align__(16) u16 Vt[64][72];
  __shared__ __align__(16) u16 Ps[4][2][16][72];
  const int tid = threadIdx.x;
  const int lane = tid & 63;
  const int wave = tid >> 6;
  const int lrow = lane & 15;
  const int quad = lane >> 4;
  const int b = blockIdx.z, h = blockIdx.y;
  const int qb = blockIdx.x * 128 + wave * 16;
  const u16* Qp = xqkv + (size_t)b * 2048 * 3072 + h * 64;
  const u16* Kp = Qp + 1024;
  const u16* Vp = Qp + 2048;

  bf16x8 qa[2][2];
  #pragma unroll
  for (int t = 0; t < 2; ++t) {
    qa[t][0] = *(const bf16x8*)&Qp[(size_t)(qb + t * 64 + lrow) * 3072 + quad * 8];
    qa[t][1] = *(const bf16x8*)&Qp[(size_t)(qb + t * 64 + lrow) * 3072 + 32 + quad * 8];
  }

  f32x4 o[2][4];
  #pragma unroll
  for (int t = 0; t < 2; ++t)
    #pragma unroll
    for (int i = 0; i < 4; ++i) o[t][i] = (f32x4){0.f, 0.f, 0.f, 0.f};
  float rsum[2] = {0.f, 0.f};

  const int ks_row = tid >> 3, ks_col = (tid & 7) * 8;
  const int v_dg = tid >> 4;
  const int v_kp = tid & 15;
  const float* maddb = madd2 + b * 2048;

  u16x8 kreg[2];
  u16x4 va[2], vb[2];
  #pragma unroll
  for (int sh = 0; sh < 2; ++sh) {
    kreg[sh] = *(const u16x8*)&Kp[(size_t)(sh * 32 + ks_row) * 3072 + ks_col];
    va[sh] = *(const u16x4*)&Vp[(size_t)(sh * 32 + 2 * v_kp) * 3072 + v_dg * 4];
    vb[sh] = *(const u16x4*)&Vp[(size_t)(sh * 32 + 2 * v_kp + 1) * 3072 + v_dg * 4];
  }

  for (int s0 = 0; s0 < 2048; s0 += 64) {
    __syncthreads();
    #pragma unroll
    for (int sh = 0; sh < 2; ++sh) {
      *(u16x8*)&Ks[sh * 32 + ks_row][ks_col] = kreg[sh];
      #pragma unroll
      for (int j = 0; j < 4; ++j) {
        u32 pk = ((u32)vb[sh][j] << 16) | (u32)va[sh][j];
        *(u32*)&Vt[v_dg * 4 + j][sh * 32 + 2 * v_kp] = pk;
      }
    }
    __syncthreads();
    if (s0 + 64 < 2048) {
      #pragma unroll
      for (int sh = 0; sh < 2; ++sh) {
        int sb = s0 + 64 + sh * 32;
        kreg[sh] = *(const u16x8*)&Kp[(size_t)(sb + ks_row) * 3072 + ks_col];
        va[sh] = *(const u16x4*)&Vp[(size_t)(sb + 2 * v_kp) * 3072 + v_dg * 4];
        vb[sh] = *(const u16x4*)&Vp[(size_t)(sb + 2 * v_kp + 1) * 3072 + v_dg * 4];
      }
    }

    bf16x8 kf[4][2], vf[4][2];
    #pragma unroll
    for (int kb = 0; kb < 4; ++kb) {
      kf[kb][0] = *(const bf16x8*)&Ks[kb * 16 + lrow][quad * 8];
      kf[kb][1] = *(const bf16x8*)&Ks[kb * 16 + lrow][32 + quad * 8];
    }
    #pragma unroll
    for (int nb = 0; nb < 4; ++nb) {
      vf[nb][0] = *(const bf16x8*)&Vt[nb * 16 + lrow][quad * 8];
      vf[nb][1] = *(const bf16x8*)&Vt[nb * 16 + lrow][32 + quad * 8];
    }

    #pragma unroll
    for (int t = 0; t < 2; ++t) {
      #pragma unroll
      for (int kb = 0; kb < 4; ++kb) {
        f32x4 z = (f32x4){0.f, 0.f, 0.f, 0.f};
        z = MFMA16(kf[kb][0], qa[t][0], z);
        z = MFMA16(kf[kb][1], qa[t][1], z);
        f32x4 m4 = *(const f32x4*)&maddb[s0 + kb * 16 + quad * 4];
        u32 pb[4];
        #pragma unroll
        for (int r = 0; r < 4; ++r) {
          float p = fast_exp2(z[r] + m4[r]);
          rsum[t] += p;
          union { float f; u32 u; } cv; cv.f = p;
          pb[r] = cv.u + 0x8000u;
        }
        u32x2 w2;
        w2[0] = __builtin_amdgcn_perm(pb[1], pb[0], 0x07060302);
        w2[1] = __builtin_amdgcn_perm(pb[3], pb[2], 0x07060302);
        *(u32x2*)&Ps[wave][t][lrow][kb * 16 + quad * 4] = w2;
      }
      #pragma unroll
      for (int kh = 0; kh < 2; ++kh) {
        bf16x8 pa = *(const bf16x8*)&Ps[wave][t][lrow][kh * 32 + quad * 8];
        #pragma unroll
        for (int nb = 0; nb < 4; ++nb)
          o[t][nb] = MFMA16(pa, vf[nb][kh], o[t][nb]);
      }
    }
  }

  #pragma unroll
  for (int t = 0; t < 2; ++t) {
    float rs = rsum[t];
    rs += __shfl_xor(rs, 16, 64);
    rs += __shfl_xor(rs, 32, 64);
    float inv = 1.f / fmaxf(rs, 1e-30f);
    #pragma unroll
    for (int r = 0; r < 4; ++r) {
      float invq = __shfl(inv, quad * 4 + r, 64);
      int q = qb + t * 64 + quad * 4 + r;
      #pragma unroll
      for (int nb = 0; nb < 4; ++nb) {
        float v = o[t][nb][r] * invq;
        ctx[((size_t)b * 2048 + q) * 1024 + h * 64 + nb * 16 + lrow] = f2bf(v);
      }
    }
  }
}

// ---------------------------------------------------------------------------
// out = LayerNorm(x + p0 + p1 + cb) * g + b  (split-K combine fused in).
// ---------------------------------------------------------------------------
template <int IN_BF, int OUT_BF>
__global__ __launch_bounds__(256) void add_ln2p(
    const void* __restrict__ xa_, const u16* __restrict__ p0,
    const u16* __restrict__ p1, const float* __restrict__ cb,
    const float* __restrict__ g, const float* __restrict__ bb,
    void* __restrict__ outp_) {
  __shared__ float red[8];
  const int tid = threadIdx.x;
  const size_t base = (size_t)blockIdx.x * 1024;
  const float* xf = (const float*)xa_;
  const u16*   xb = (const u16*)xa_;
  float v[4];
  float s = 0.f;
  #pragma unroll
  for (int i = 0; i < 4; ++i) {
    int c = i * 256 + tid;
    float xv = IN_BF ? bf2f(xb[base + c]) : xf[base + c];
    v[i] = xv + bf2f(p0[base + c]) + bf2f(p1[base + c]) + cb[c];
    s += v[i];
  }
  #pragma unroll
  for (int off = 32; off > 0; off >>= 1) s += __shfl_down(s, off, 64);
  if ((tid & 63) == 0) red[tid >> 6] = s;
  __syncthreads();
  float mean = (red[0] + red[1] + red[2] + red[3]) * (1.f / 1024.f);
  float s2 = 0.f;
  #pragma unroll
  for (int i = 0; i < 4; ++i) { float d = v[i] - mean; s2 += d * d; }
  #pragma unroll
  for (int off = 32; off > 0; off >>= 1) s2 += __shfl_down(s2, off, 64);
  if ((tid & 63) == 0) red[4 + (tid >> 6)] = s2;
  __syncthreads();
  float var = (red[4] + red[5] + red[6] + red[7]) * (1.f / 1024.f);
  float rstd = rsqrtf(var + 1e-5f);
  #pragma unroll
  for (int i = 0; i < 4; ++i) {
    int c = i * 256 + tid;
    float r = (v[i] - mean) * rstd * g[c] + bb[c];
    if (OUT_BF) ((u16*)outp_)[base + c] = f2bf(r);
    else        ((float*)outp_)[base + c] = r;
  }
}

// ---------------------------------------------------------------------------
extern "C" void kernel_launch(void* const* d_in, const int* in_sizes, int n_in,
                              void* d_out, int out_size, void* d_ws, size_t ws_size,
                              hipStream_t stream) {
  (void)in_sizes; (void)n_in; (void)out_size; (void)ws_size;
  const float* x    = (const float*)d_in[0];
  const int*   mask = (const int*)d_in[1];
  const float* Wq   = (const float*)d_in[2];
  const float* bq   = (const float*)d_in[3];
  const float* Wk   = (const float*)d_in[4];
  const float* bk   = (const float*)d_in[5];
  const float* Wv   = (const float*)d_in[6];
  const float* bv   = (const float*)d_in[7];
  const float* Wo   = (const float*)d_in[8];
  const float* bo   = (const float*)d_in[9];
  const float* ln1g = (const float*)d_in[10];
  const float* ln1b = (const float*)d_in[11];
  const float* ln2g = (const float*)d_in[12];
  const float* ln2b = (const float*)d_in[13];
  const float* W1   = (const float*)d_in[14];
  const float* b1   = (const float*)d_in[15];
  const float* W2   = (const float*)d_in[16];
  const float* b2   = (const float*)d_in[17];
  float* out = (float*)d_out;

  char* ws = (char*)d_ws;
  u16*   Wqkv_t = (u16*)(ws + 0);           // 6 MB; later FF2 partial0 (8 MB)
  u16*   fp     = (u16*)(ws + 0);           // FF2 partials: [0,8M) + [8M,16M)
  u16*   Wo_t   = (u16*)(ws + 6291456);     // 2 MB
  u16*   W1_t   = (u16*)(ws + 8388608);     // 8 MB; later FF2 partial1
  u16*   W2_t   = (u16*)(ws + 16777216);    // 8 MB
  u16*   xqkv   = (u16*)(ws + 25165824);    // [4096][3072] bf16, 24 MB
  u16*   wp     = (u16*)(ws + 25165824);    // Wo partials 2x8 MB (xqkv dead after attn)
  u16*   xb     = (u16*)(ws + 50331648);    // 8 MB (dead after QKV gemm)
  u16*   ctx    = (u16*)(ws + 50331648);    // [4096][1024] bf16, 8 MB (after attn)
  u16*   ff1    = (u16*)(ws + 25165824);    // 32 MB (overlays xqkv+ctx; live LN1->FF2)
  u16*   hbuf   = (u16*)(ws + 67108864);    // 8 MB
  float* biasq  = (float*)(ws + 75497472);  // 3072 f32
  float* madd2  = (float*)(ws + 75509760);  // 4096 f32  (total ~75.5 MB)

  prep_all<<<16412, 256, 0, stream>>>(bq, bk, bv, mask, biasq, madd2,
                                      x, xb, Wq, Wk, Wv, Wqkv_t,
                                      Wo, W1, W2, Wo_t, W1_t, W2_t);

  // QKV: 256^2 8-wave template, grid 12x16 = 192 blocks
  gemm256<0><<<dim3(12, 16), 512, 131072, stream>>>(xb, Wqkv_t, biasq, xqkv,
                                                    4096, 3072, 1024);
  attn_kernel<<<dim3(16, 16, 2), 256, 0, stream>>>(xqkv, madd2, ctx);
  // Wo projection, split-K=2 -> bf16 partials in dead xqkv space
  gemm_splitk<<<dim3(8, 32, 2), 256, 0, stream>>>(ctx, Wo_t, wp, 4096, 1024, 1024);
  add_ln2p<0, 1><<<4096, 256, 0, stream>>>(x, wp, wp + 4194304, bo,
                                           ln1g, ln1b, hbuf);
  // FF1: 256^2 template with fused relu, grid 16x16 = 256 blocks
  gemm256<1><<<dim3(16, 16), 512, 131072, stream>>>(hbuf, W1_t, b1, ff1,
                                                    4096, 4096, 1024);
  // FF2, split-K=2 -> partials in dead Wqkv_t/W1_t space
  gemm_splitk<<<dim3(8, 32, 2), 256, 0, stream>>>(ff1, W2_t, fp, 4096, 1024, 4096);
  add_ln2p<1, 0><<<4096, 256, 0, stream>>>(hbuf, fp, fp + 4194304, b2,
                                           ln2g, ln2b, out);
}

// Round 8
// 347.073 us; speedup vs baseline: 1.1848x; 1.0558x over previous
//
#include <hip/hip_runtime.h>
#include <cstdint>
#include <cstddef>

typedef unsigned short u16;
typedef unsigned int   u32;
typedef unsigned short u16x4 __attribute__((ext_vector_type(4)));
typedef unsigned short u16x8 __attribute__((ext_vector_type(8)));
typedef unsigned int   u32x2 __attribute__((ext_vector_type(2)));
typedef __bf16 bf16x8 __attribute__((ext_vector_type(8)));
typedef float f32x4 __attribute__((ext_vector_type(4)));

#define MFMA16(a, b, c) __builtin_amdgcn_mfma_f32_16x16x32_bf16((a), (b), (c), 0, 0, 0)

__device__ __forceinline__ float bf2f(u16 h) {
  union { unsigned u; float f; } v; v.u = ((unsigned)h) << 16; return v.f;
}
__device__ __forceinline__ u16 f2bf(float f) {
  union { float f; unsigned u; } v; v.f = f;
  unsigned r = v.u + 0x7fffu + ((v.u >> 16) & 1u);
  return (u16)(r >> 16);
}
__device__ __forceinline__ void gll16(const u16* g, u16* l) {
  __builtin_amdgcn_global_load_lds(
      (const __attribute__((address_space(1))) void*)g,
      (__attribute__((address_space(3))) void*)l, 16, 0, 0);
}
__device__ __forceinline__ float fast_exp2(float x) {
#if __has_builtin(__builtin_amdgcn_exp2f)
  return __builtin_amdgcn_exp2f(x);
#else
  return exp2f(x);
#endif
}

// ---------------------------------------------------------------------------
// Fused prologue: one dispatch replaces prep_small + cvt_x + transpose_qkv +
// transpose_w. Block-id ranges:
//   [0,28)        prep_small   [28,4124)  cvt_x
//   [4124,7196)   transpose_qkv (Wq pre-scaled by 0.125*log2e)
//   [7196,16412)  transpose_w
// ---------------------------------------------------------------------------
__global__ __launch_bounds__(256) void prep_all(
    const float* __restrict__ bq, const float* __restrict__ bk,
    const float* __restrict__ bv, const int* __restrict__ mask,
    float* __restrict__ biasq, float* __restrict__ madd2,
    const float* __restrict__ x, u16* __restrict__ xb,
    const float* __restrict__ Wq, const float* __restrict__ Wk,
    const float* __restrict__ Wv, u16* __restrict__ Wqkv_t,
    const float* __restrict__ Wo, const float* __restrict__ W1,
    const float* __restrict__ W2, u16* __restrict__ Wo_t,
    u16* __restrict__ W1_t, u16* __restrict__ W2_t) {
  __shared__ u16 tile[32][33];
  const int id = blockIdx.x;
  const int tid = threadIdx.x;

  if (id < 28) {
    int i = id * 256 + tid;
    if (i < 3072) {
      biasq[i] = (i < 1024) ? bq[i] * 0.18033688f
                            : (i < 2048 ? bk[i - 1024] : bv[i - 2048]);
    } else if (i < 7168) {
      int j = i - 3072;
      madd2[j] = mask[j] ? -23.083120f : -1.442695e9f;  // (-16|-1e9)*log2e
    }
    return;
  }
  if (id < 4124) {
    int i = ((id - 28) * 256 + tid) * 4;
    const float4 v = *(const float4*)&x[i];
    u16x4 o;
    o[0] = f2bf(v.x); o[1] = f2bf(v.y); o[2] = f2bf(v.z); o[3] = f2bf(v.w);
    *(u16x4*)&xb[i] = o;
    return;
  }
  if (id < 7196) {
    int t = id - 4124;
    const int bx = t & 1, by = (t >> 1) & 31, z = t >> 6;
    const int which = z >> 4, h = z & 15;
    const float* in = (which == 0 ? Wq : (which == 1 ? Wk : Wv)) + (size_t)h * 1024 * 64;
    u16* out = Wqkv_t + ((size_t)which * 1024 + h * 64) * 1024;   // [64][1024]
    const float sc = (which == 0) ? 0.18033688f : 1.0f;           // 0.125*log2e
    const int tx = tid & 31, ty = tid >> 5;
    const int r0 = by * 32, c0 = bx * 32;
    #pragma unroll
    for (int i = 0; i < 32; i += 8)
      tile[ty + i][tx] = f2bf(in[(size_t)(r0 + ty + i) * 64 + c0 + tx] * sc);
    __syncthreads();
    #pragma unroll
    for (int i = 0; i < 32; i += 8)
      out[(size_t)(c0 + ty + i) * 1024 + r0 + tx] = tile[tx][ty + i];
    return;
  }
  {
    int t0 = id - 7196;
    const float* in; u16* outp; int R, C, cx, ry;
    if (t0 < 1024)      { in = Wo; outp = Wo_t; R = 1024; C = 1024; cx = t0 & 31;  ry = t0 >> 5; }
    else if (t0 < 5120) { int t = t0 - 1024; in = W1; outp = W1_t; R = 1024; C = 4096; cx = t & 127; ry = t >> 7; }
    else                { int t = t0 - 5120; in = W2; outp = W2_t; R = 4096; C = 1024; cx = t & 31;  ry = t >> 5; }
    const int tx = tid & 31, ty = tid >> 5;
    const int r0 = ry * 32, c0 = cx * 32;
    #pragma unroll
    for (int i = 0; i < 32; i += 8)
      tile[ty + i][tx] = f2bf(in[(size_t)(r0 + ty + i) * C + c0 + tx]);
    __syncthreads();
    #pragma unroll
    for (int i = 0; i < 32; i += 8)
      outp[(size_t)(c0 + ty + i) * R + r0 + tx] = tile[tx][ty + i];
  }
}

// XCD-chunked tile remap (T1), 128-tiles. nwg must be %8==0.
__device__ __forceinline__ void xcd_tiles(int& m0, int& n0) {
  const int gX = gridDim.x, gY = gridDim.y;
  int n = blockIdx.y * gX + blockIdx.x;
  int cpx = (gX * gY) >> 3;
  int t = (n & 7) * cpx + (n >> 3);
  n0 = (t / gY) * 128;
  m0 = (t % gY) * 128;
}
// 256-tile variant for gemm256.
__device__ __forceinline__ void xcd_tiles256(int& m0, int& n0) {
  const int gX = gridDim.x, gY = gridDim.y;
  int n = blockIdx.y * gX + blockIdx.x;
  int cpx = (gX * gY) >> 3;
  int t = (n & 7) * cpx + (n >> 3);
  n0 = (t / gY) * 256;
  m0 = (t % gY) * 256;
}

// ---------------------------------------------------------------------------
// gemm256 v2: 256x256 tile, BK=64, 8 waves, COUNTED-VMCNT pipeline + LDS
// XOR-swizzle (T2+T3+T4+T5 port of the 8-phase template; K=1024 only).
// Wave layout 1Mx8N: per-wave 256 rows x 32 cols (acc[16][2]) so A-row
// consumption order matches the staged 64-row chunk order.
// LDS [2 buf][A 256x64 | B 256x64] = 131072 B. Staged chunk s = 64 rows:
// issue order per K-step: B0,B1,B2,B3,A0,A1,A2,A3 (2 gll16 per phase).
// Phase P of step t: vmcnt(N) -> s_barrier -> ds_read (swizzled) ->
// stage 2 chunks of t+1 -> setprio(1) 16 MFMA setprio(0).
// Steady-state N = 3/4/5/6 (never 0); last K-step peeled with 3/2/1/0.
// Swizzle: LDS[row][c8] holds global[row][c8 ^ (row&7)] (16B units);
// gll16 dest stays linear, source col pre-swizzled (rule #21).
// MODE 0: bias, 1: bias+relu.
// ---------------------------------------------------------------------------
template <int MODE>
__global__ __launch_bounds__(512, 2) void gemm256(
    const u16* __restrict__ A, const u16* __restrict__ Bt,
    const float* __restrict__ bias, u16* __restrict__ C,
    int M, int N, int K) {
  extern __shared__ __align__(16) u16 lds[];
  u16* As = lds;            // [2][256][64] (chunk s = rows s*64..s*64+63)
  u16* Bs = lds + 32768;
  const int tid = threadIdx.x;   // 0..511
  const int lane = tid & 63, wave = tid >> 6;
  const int lrow = lane & 15, quad = lane >> 4;
  int m0, n0;
  xcd_tiles256(m0, n0);

  const int sw = lrow & 7;                        // read-side swizzle key
  const int srow = tid >> 3;                      // staging row within chunk
  const int scol = ((tid & 7) ^ (srow & 7)) * 8;  // pre-swizzled source col
  const u16* gA = A  + (size_t)(m0 + srow) * K + scol;
  const u16* gB = Bt + (size_t)(n0 + srow) * K + scol;
  const int tid8 = tid * 8;

  f32x4 acc[16][2];
  #pragma unroll
  for (int i = 0; i < 16; ++i) {
    acc[i][0] = (f32x4){0.f, 0.f, 0.f, 0.f};
    acc[i][1] = (f32x4){0.f, 0.f, 0.f, 0.f};
  }

  const int NT = K >> 6;

  // prologue: stage step 0 -> buf 0 (B chunks 0..3 then A chunks 0..3)
  #pragma unroll
  for (int s = 0; s < 4; ++s)
    gll16(gB + (size_t)(s * 64) * K, Bs + s * 4096 + tid8);
  #pragma unroll
  for (int s = 0; s < 4; ++s)
    gll16(gA + (size_t)(s * 64) * K, As + s * 4096 + tid8);

#define DSA(fr, kh) (*(const bf16x8*)&Ab[((fr) * 16 + lrow) * 64 + ((((kh) * 4 + quad) ^ sw) * 8)])
#define DSB(fc, kh) (*(const bf16x8*)&Bb[(wave * 32 + (fc) * 16 + lrow) * 64 + ((((kh) * 4 + quad) ^ sw) * 8)])
#define STG_B(s) gll16(gB + koff + (size_t)((s) * 64) * K, Bd + (s) * 4096)
#define STG_A(s) gll16(gA + koff + (size_t)((s) * 64) * K, Ad + (s) * 4096)
#define KPHASE(P, VMSTR, STEXPR)                                              \
    asm volatile("s_waitcnt " VMSTR ::: "memory");                            \
    __builtin_amdgcn_s_barrier();                                             \
    asm volatile("" ::: "memory");                                            \
    {                                                                         \
      bf16x8 af[4][2];                                                        \
      if ((P) == 0) {                                                         \
        _Pragma("unroll")                                                     \
        for (int fc = 0; fc < 2; ++fc) {                                      \
          bfr[fc][0] = DSB(fc, 0);                                            \
          bfr[fc][1] = DSB(fc, 1);                                            \
        }                                                                     \
      }                                                                       \
      _Pragma("unroll")                                                       \
      for (int j = 0; j < 4; ++j) {                                           \
        af[j][0] = DSA((P) * 4 + j, 0);                                       \
        af[j][1] = DSA((P) * 4 + j, 1);                                       \
      }                                                                       \
      STEXPR                                                                  \
      __builtin_amdgcn_s_setprio(1);                                          \
      _Pragma("unroll")                                                       \
      for (int j = 0; j < 4; ++j) {                                           \
        _Pragma("unroll")                                                     \
        for (int fc = 0; fc < 2; ++fc) {                                      \
          acc[(P) * 4 + j][fc] = MFMA16(af[j][0], bfr[fc][0], acc[(P) * 4 + j][fc]); \
          acc[(P) * 4 + j][fc] = MFMA16(af[j][1], bfr[fc][1], acc[(P) * 4 + j][fc]); \
        }                                                                     \
      }                                                                       \
      __builtin_amdgcn_s_setprio(0);                                          \
    }

  for (int t = 0; t < NT - 1; ++t) {
    const int p = t & 1;
    const u16* Ab = As + p * 16384;
    const u16* Bb = Bs + p * 16384;
    u16* Ad = As + (p ^ 1) * 16384 + tid8;
    u16* Bd = Bs + (p ^ 1) * 16384 + tid8;
    const size_t koff = (size_t)(t + 1) * 64;
    bf16x8 bfr[2][2];
    KPHASE(0, "vmcnt(3)", STG_B(0); STG_B(1);)
    KPHASE(1, "vmcnt(4)", STG_B(2); STG_B(3);)
    KPHASE(2, "vmcnt(5)", STG_A(0); STG_A(1);)
    KPHASE(3, "vmcnt(6)", STG_A(2); STG_A(3);)
  }
  {
    const int p = (NT - 1) & 1;
    const u16* Ab = As + p * 16384;
    const u16* Bb = Bs + p * 16384;
    bf16x8 bfr[2][2];
    KPHASE(0, "vmcnt(3)", )
    KPHASE(1, "vmcnt(2)", )
    KPHASE(2, "vmcnt(1)", )
    KPHASE(3, "vmcnt(0)", )
  }
#undef DSA
#undef DSB
#undef STG_B
#undef STG_A
#undef KPHASE

  #pragma unroll
  for (int fr = 0; fr < 16; ++fr) {
    int rowb = m0 + fr * 16 + quad * 4;
    #pragma unroll
    for (int fc = 0; fc < 2; ++fc) {
      int col = n0 + wave * 32 + fc * 16 + lrow;
      float bv = bias[col];
      #pragma unroll
      for (int r = 0; r < 4; ++r) {
        float v = acc[fr][fc][r] + bv;
        if (MODE == 1) v = fmaxf(v, 0.f);
        C[(size_t)(rowb + r) * N + col] = f2bf(v);
      }
    }
  }
}

// ---------------------------------------------------------------------------
// Split-K GEMM 128x128, BK=64: grid (N/128, M/128, 2).
// ---------------------------------------------------------------------------
__global__ __launch_bounds__(256) void gemm_splitk(
    const u16* __restrict__ A, const u16* __restrict__ Bt,
    u16* __restrict__ Cp, int M, int N, int K) {
  __shared__ __align__(16) u16 As[2][128 * 32];
  __shared__ __align__(16) u16 Bs[2][128 * 32];
  const int tid = threadIdx.x;
  const int lane = tid & 63;
  const int wave = tid >> 6;
  int m0, n0;
  xcd_tiles(m0, n0);
  const int kz = blockIdx.z;
  const int Kh = K >> 1;
  const int kbase = kz * Kh;
  const int wr = (wave >> 1) * 64;
  const int wc = (wave & 1) * 64;
  const int lrow = lane & 15;
  const int quad = lane >> 4;

  const int srow = lane >> 2;
  const int scol = (lane & 3) * 8;
  const u16* gA1 = &A[(size_t)(m0 + wave * 16 + srow) * K + kbase + scol];
  const u16* gA2 = &A[(size_t)(m0 + 64 + wave * 16 + srow) * K + kbase + scol];
  const u16* gB1 = &Bt[(size_t)(n0 + wave * 16 + srow) * K + kbase + scol];
  const u16* gB2 = &Bt[(size_t)(n0 + 64 + wave * 16 + srow) * K + kbase + scol];
  const int so1 = (wave * 16) * 32;
  const int so2 = (wave * 16 + 64) * 32;
  u16* C = Cp + (size_t)kz * M * N;

  f32x4 acc[4][4];
  #pragma unroll
  for (int i = 0; i < 4; ++i)
    #pragma unroll
    for (int j = 0; j < 4; ++j)
      acc[i][j] = (f32x4){0.f, 0.f, 0.f, 0.f};

  for (int k0 = 0; k0 < Kh; k0 += 64) {
    gll16(gA1 + k0, &As[0][so1]);
    gll16(gA2 + k0, &As[0][so2]);
    gll16(gB1 + k0, &Bs[0][so1]);
    gll16(gB2 + k0, &Bs[0][so2]);
    gll16(gA1 + k0 + 32, &As[1][so1]);
    gll16(gA2 + k0 + 32, &As[1][so2]);
    gll16(gB1 + k0 + 32, &Bs[1][so1]);
    gll16(gB2 + k0 + 32, &Bs[1][so2]);
    __syncthreads();
    #pragma unroll
    for (int kb = 0; kb < 2; ++kb) {
      bf16x8 af[4], bfr[4];
      #pragma unroll
      for (int i = 0; i < 4; ++i) {
        af[i]  = *(const bf16x8*)&As[kb][(wr + i * 16 + lrow) * 32 + quad * 8];
        bfr[i] = *(const bf16x8*)&Bs[kb][(wc + i * 16 + lrow) * 32 + quad * 8];
      }
      #pragma unroll
      for (int fr = 0; fr < 4; ++fr)
        #pragma unroll
        for (int fc = 0; fc < 4; ++fc)
          acc[fr][fc] = MFMA16(af[fr], bfr[fc], acc[fr][fc]);
    }
    __syncthreads();
  }

  #pragma unroll
  for (int fr = 0; fr < 4; ++fr) {
    int rowb = m0 + wr + fr * 16 + quad * 4;
    #pragma unroll
    for (int fc = 0; fc < 4; ++fc) {
      int col = n0 + wc + fc * 16 + lrow;
      #pragma unroll
      for (int r = 0; r < 4; ++r)
        C[(size_t)(rowb + r) * N + col] = f2bf(acc[fr][fc][r]);
    }
  }
}

// ---------------------------------------------------------------------------
// Flash attention — r5 form verbatim (75.5 us measured): 2 barriers/step,
// t=2 q-tiles/wave, 128 q-rows/block, grid (16,16,2), no setprio.
// Vt trimmed to [64][72]; p = exp2(z + madd) (Wq pre-scaled). LDS 36864 B.
// ---------------------------------------------------------------------------
__global__ __launch_bounds__(256) void attn_kernel(
    const u16* __restrict__ xqkv, const float* __restrict__ madd2,
    u16* __restrict__ ctx) {
  __shared__ __align__(16) u16 Ks[64][72];
  __shared__ __align__(16) u16 Vt[64][72];
  __shared__ __align__(16) u16 Ps[4][2][16][72];
  const int tid = threadIdx.x;
  const int lane = tid & 63;
  const int wave = tid >> 6;
  const int lrow = lane & 15;
  const int quad = lane >> 4;
  const int b = blockIdx.z, h = blockIdx.y;
  const int qb = blockIdx.x * 128 + wave * 16;
  const u16* Qp = xqkv + (size_t)b * 2048 * 3072 + h * 64;
  const u16* Kp = Qp + 1024;
  const u16* Vp = Qp + 2048;

  bf16x8 qa[2][2];
  #pragma unroll
  for (int t = 0; t < 2; ++t) {
    qa[t][0] = *(const bf16x8*)&Qp[(size_t)(qb + t * 64 + lrow) * 3072 + quad * 8];
    qa[t][1] = *(const bf16x8*)&Qp[(size_t)(qb + t * 64 + lrow) * 3072 + 32 + quad * 8];
  }

  f32x4 o[2][4];
  #pragma unroll
  for (int t = 0; t < 2; ++t)
    #pragma unroll
    for (int i = 0; i < 4; ++i) o[t][i] = (f32x4){0.f, 0.f, 0.f, 0.f};
  float rsum[2] = {0.f, 0.f};

  const int ks_row = tid >> 3, ks_col = (tid & 7) * 8;
  const int v_dg = tid >> 4;
  const int v_kp = tid & 15;
  const float* maddb = madd2 + b * 2048;

  u16x8 kreg[2];
  u16x4 va[2], vb[2];
  #pragma unroll
  for (int sh = 0; sh < 2; ++sh) {
    kreg[sh] = *(const u16x8*)&Kp[(size_t)(sh * 32 + ks_row) * 3072 + ks_col];
    va[sh] = *(const u16x4*)&Vp[(size_t)(sh * 32 + 2 * v_kp) * 3072 + v_dg * 4];
    vb[sh] = *(const u16x4*)&Vp[(size_t)(sh * 32 + 2 * v_kp + 1) * 3072 + v_dg * 4];
  }

  for (int s0 = 0; s0 < 2048; s0 += 64) {
    __syncthreads();
    #pragma unroll
    for (int sh = 0; sh < 2; ++sh) {
      *(u16x8*)&Ks[sh * 32 + ks_row][ks_col] = kreg[sh];
      #pragma unroll
      for (int j = 0; j < 4; ++j) {
        u32 pk = ((u32)vb[sh][j] << 16) | (u32)va[sh][j];
        *(u32*)&Vt[v_dg * 4 + j][sh * 32 + 2 * v_kp] = pk;
      }
    }
    __syncthreads();
    if (s0 + 64 < 2048) {
      #pragma unroll
      for (int sh = 0; sh < 2; ++sh) {
        int sb = s0 + 64 + sh * 32;
        kreg[sh] = *(const u16x8*)&Kp[(size_t)(sb + ks_row) * 3072 + ks_col];
        va[sh] = *(const u16x4*)&Vp[(size_t)(sb + 2 * v_kp) * 3072 + v_dg * 4];
        vb[sh] = *(const u16x4*)&Vp[(size_t)(sb + 2 * v_kp + 1) * 3072 + v_dg * 4];
      }
    }

    bf16x8 kf[4][2], vf[4][2];
    #pragma unroll
    for (int kb = 0; kb < 4; ++kb) {
      kf[kb][0] = *(const bf16x8*)&Ks[kb * 16 + lrow][quad * 8];
      kf[kb][1] = *(const bf16x8*)&Ks[kb * 16 + lrow][32 + quad * 8];
    }
    #pragma unroll
    for (int nb = 0; nb < 4; ++nb) {
      vf[nb][0] = *(const bf16x8*)&Vt[nb * 16 + lrow][quad * 8];
      vf[nb][1] = *(const bf16x8*)&Vt[nb * 16 + lrow][32 + quad * 8];
    }

    #pragma unroll
    for (int t = 0; t < 2; ++t) {
      #pragma unroll
      for (int kb = 0; kb < 4; ++kb) {
        f32x4 z = (f32x4){0.f, 0.f, 0.f, 0.f};
        z = MFMA16(kf[kb][0], qa[t][0], z);
        z = MFMA16(kf[kb][1], qa[t][1], z);
        f32x4 m4 = *(const f32x4*)&maddb[s0 + kb * 16 + quad * 4];
        u32 pb[4];
        #pragma unroll
        for (int r = 0; r < 4; ++r) {
          float p = fast_exp2(z[r] + m4[r]);
          rsum[t] += p;
          union { float f; u32 u; } cv; cv.f = p;
          pb[r] = cv.u + 0x8000u;
        }
        u32x2 w2;
        w2[0] = __builtin_amdgcn_perm(pb[1], pb[0], 0x07060302);
        w2[1] = __builtin_amdgcn_perm(pb[3], pb[2], 0x07060302);
        *(u32x2*)&Ps[wave][t][lrow][kb * 16 + quad * 4] = w2;
      }
      #pragma unroll
      for (int kh = 0; kh < 2; ++kh) {
        bf16x8 pa = *(const bf16x8*)&Ps[wave][t][lrow][kh * 32 + quad * 8];
        #pragma unroll
        for (int nb = 0; nb < 4; ++nb)
          o[t][nb] = MFMA16(pa, vf[nb][kh], o[t][nb]);
      }
    }
  }

  #pragma unroll
  for (int t = 0; t < 2; ++t) {
    float rs = rsum[t];
    rs += __shfl_xor(rs, 16, 64);
    rs += __shfl_xor(rs, 32, 64);
    float inv = 1.f / fmaxf(rs, 1e-30f);
    #pragma unroll
    for (int r = 0; r < 4; ++r) {
      float invq = __shfl(inv, quad * 4 + r, 64);
      int q = qb + t * 64 + quad * 4 + r;
      #pragma unroll
      for (int nb = 0; nb < 4; ++nb) {
        float v = o[t][nb][r] * invq;
        ctx[((size_t)b * 2048 + q) * 1024 + h * 64 + nb * 16 + lrow] = f2bf(v);
      }
    }
  }
}

// ---------------------------------------------------------------------------
// out = LayerNorm(x + p0 + p1 + cb) * g + b  (split-K combine fused in).
// ---------------------------------------------------------------------------
template <int IN_BF, int OUT_BF>
__global__ __launch_bounds__(256) void add_ln2p(
    const void* __restrict__ xa_, const u16* __restrict__ p0,
    const u16* __restrict__ p1, const float* __restrict__ cb,
    const float* __restrict__ g, const float* __restrict__ bb,
    void* __restrict__ outp_) {
  __shared__ float red[8];
  const int tid = threadIdx.x;
  const size_t base = (size_t)blockIdx.x * 1024;
  const float* xf = (const float*)xa_;
  const u16*   xb = (const u16*)xa_;
  float v[4];
  float s = 0.f;
  #pragma unroll
  for (int i = 0; i < 4; ++i) {
    int c = i * 256 + tid;
    float xv = IN_BF ? bf2f(xb[base + c]) : xf[base + c];
    v[i] = xv + bf2f(p0[base + c]) + bf2f(p1[base + c]) + cb[c];
    s += v[i];
  }
  #pragma unroll
  for (int off = 32; off > 0; off >>= 1) s += __shfl_down(s, off, 64);
  if ((tid & 63) == 0) red[tid >> 6] = s;
  __syncthreads();
  float mean = (red[0] + red[1] + red[2] + red[3]) * (1.f / 1024.f);
  float s2 = 0.f;
  #pragma unroll
  for (int i = 0; i < 4; ++i) { float d = v[i] - mean; s2 += d * d; }
  #pragma unroll
  for (int off = 32; off > 0; off >>= 1) s2 += __shfl_down(s2, off, 64);
  if ((tid & 63) == 0) red[4 + (tid >> 6)] = s2;
  __syncthreads();
  float var = (red[4] + red[5] + red[6] + red[7]) * (1.f / 1024.f);
  float rstd = rsqrtf(var + 1e-5f);
  #pragma unroll
  for (int i = 0; i < 4; ++i) {
    int c = i * 256 + tid;
    float r = (v[i] - mean) * rstd * g[c] + bb[c];
    if (OUT_BF) ((u16*)outp_)[base + c] = f2bf(r);
    else        ((float*)outp_)[base + c] = r;
  }
}

// ---------------------------------------------------------------------------
extern "C" void kernel_launch(void* const* d_in, const int* in_sizes, int n_in,
                              void* d_out, int out_size, void* d_ws, size_t ws_size,
                              hipStream_t stream) {
  (void)in_sizes; (void)n_in; (void)out_size; (void)ws_size;
  const float* x    = (const float*)d_in[0];
  const int*   mask = (const int*)d_in[1];
  const float* Wq   = (const float*)d_in[2];
  const float* bq   = (const float*)d_in[3];
  const float* Wk   = (const float*)d_in[4];
  const float* bk   = (const float*)d_in[5];
  const float* Wv   = (const float*)d_in[6];
  const float* bv   = (const float*)d_in[7];
  const float* Wo   = (const float*)d_in[8];
  const float* bo   = (const float*)d_in[9];
  const float* ln1g = (const float*)d_in[10];
  const float* ln1b = (const float*)d_in[11];
  const float* ln2g = (const float*)d_in[12];
  const float* ln2b = (const float*)d_in[13];
  const float* W1   = (const float*)d_in[14];
  const float* b1   = (const float*)d_in[15];
  const float* W2   = (const float*)d_in[16];
  const float* b2   = (const float*)d_in[17];
  float* out = (float*)d_out;

  char* ws = (char*)d_ws;
  u16*   Wqkv_t = (u16*)(ws + 0);           // 6 MB; later FF2 partial0 (8 MB)
  u16*   fp     = (u16*)(ws + 0);           // FF2 partials: [0,8M) + [8M,16M)
  u16*   Wo_t   = (u16*)(ws + 6291456);     // 2 MB
  u16*   W1_t   = (u16*)(ws + 8388608);     // 8 MB; later FF2 partial1
  u16*   W2_t   = (u16*)(ws + 16777216);    // 8 MB
  u16*   xqkv   = (u16*)(ws + 25165824);    // [4096][3072] bf16, 24 MB
  u16*   wp     = (u16*)(ws + 25165824);    // Wo partials 2x8 MB (xqkv dead after attn)
  u16*   xb     = (u16*)(ws + 50331648);    // 8 MB (dead after QKV gemm)
  u16*   ctx    = (u16*)(ws + 50331648);    // [4096][1024] bf16, 8 MB (after attn)
  u16*   ff1    = (u16*)(ws + 25165824);    // 32 MB (overlays xqkv+ctx; live LN1->FF2)
  u16*   hbuf   = (u16*)(ws + 67108864);    // 8 MB
  float* biasq  = (float*)(ws + 75497472);  // 3072 f32
  float* madd2  = (float*)(ws + 75509760);  // 4096 f32  (total ~75.5 MB)

  prep_all<<<16412, 256, 0, stream>>>(bq, bk, bv, mask, biasq, madd2,
                                      x, xb, Wq, Wk, Wv, Wqkv_t,
                                      Wo, W1, W2, Wo_t, W1_t, W2_t);

  // QKV: 256^2 counted-vmcnt template, grid 12x16 = 192 blocks
  gemm256<0><<<dim3(12, 16), 512, 131072, stream>>>(xb, Wqkv_t, biasq, xqkv,
                                                    4096, 3072, 1024);
  attn_kernel<<<dim3(16, 16, 2), 256, 0, stream>>>(xqkv, madd2, ctx);
  // Wo projection, split-K=2 -> bf16 partials in dead xqkv space
  gemm_splitk<<<dim3(8, 32, 2), 256, 0, stream>>>(ctx, Wo_t, wp, 4096, 1024, 1024);
  add_ln2p<0, 1><<<4096, 256, 0, stream>>>(x, wp, wp + 4194304, bo,
                                           ln1g, ln1b, hbuf);
  // FF1: 256^2 counted-vmcnt template with fused relu, grid 16x16 = 256 blocks
  gemm256<1><<<dim3(16, 16), 512, 131072, stream>>>(hbuf, W1_t, b1, ff1,
                                                    4096, 4096, 1024);
  // FF2, split-K=2 -> partials in dead Wqkv_t/W1_t space
  gemm_splitk<<<dim3(8, 32, 2), 256, 0, stream>>>(ff1, W2_t, fp, 4096, 1024, 4096);
  add_ln2p<1, 0><<<4096, 256, 0, stream>>>(hbuf, fp, fp + 4194304, b2,
                                           ln2g, ln2b, out);
}